// Round 5
// baseline (107.243 us; speedup 1.0000x reference)
//
#include <hip/hip_runtime.h>

// ClusteredAttention via bf16 MFMA, fragment-swizzled operands. B=2,L=2048,H=8,D=64.
//   kswz = bf16(sum_v key · log2e)  frag-linear   (pool role of prep kernel)
//   vswz = bf16(V) transposed+permuted frag-linear (vswz role of prep kernel)
//   S^T = K.Q (mfma 32x32x16; Q pre-scaled by 1/8) ; P = exp2(S^T) ; O = P.V
//   out = O / rowsum(P)
// Round-4 lessons: ws_size = 256 MiB (fills in profile) -> flat 4.5 MiB layout.
// Attn was L2-BW bound (532 MB reads); this round: 64 q-rows/block halves that,
// exp2 folding removes 16 v_mul/iter, prep fused to one dispatch, XCD swizzle.

#define BB 2
#define LL 2048
#define HH 8
#define DD 64

typedef __attribute__((ext_vector_type(8)))  short  short8;   // 8 bf16 = 4 VGPR
typedef __attribute__((ext_vector_type(16))) float  float16v; // 32x32 C/D frag

static __device__ inline unsigned short f2bf(float x) {       // RNE
    union { float f; unsigned u; } v; v.f = x;
    unsigned r = v.u + 0x7FFF + ((v.u >> 16) & 1);
    return (unsigned short)(r >> 16);
}
static __device__ inline unsigned pk_bf2(float x, float y) {
    return (unsigned)f2bf(x) | ((unsigned)f2bf(y) << 16);
}

// ------------------- fused prep: V-swizzle + K-pool-swizzle ------------------
// blocks [0,512): vswz role — chunk ((bh*64+T)*4 + t*2 + vh) is 1KB, lane
//   (half*32+ln) holds V[m=T*32+perm(t,half,jj)][s=vh*32+ln], jj=0..7.
// blocks [512,640): pool role — chunk ((b*64+T)*4+ks) is 1KB, lane (hf*32+ln)
//   holds log2e * sum_v key[b, T*32+ln, v, ks*16+hf*8 .. +8]. Contiguous stores.
__global__ __launch_bounds__(256)
void prep_kernel(const float* __restrict__ key, const float* __restrict__ value,
                 unsigned short* __restrict__ kswz,
                 unsigned short* __restrict__ vswz) {
    __shared__ __align__(16) float Vl[64][68];
    int bid = blockIdx.x;
    int tid = threadIdx.x;

    if (bid < 512) {
        int mt = bid & 31, bh = bid >> 5;
        int h = bh & 7, b = bh >> 3;
        int m0 = mt * 64;
#pragma unroll
        for (int k = 0; k < 4; ++k) {
            int f = tid + k * 256;        // 64 rows x 16 float4
            int r = f >> 4;
            int cc = (f & 15) * 4;
            float4 t = *(const float4*)(value +
                (((size_t)(b * LL + m0 + r)) * HH + h) * DD + cc);
            *(float4*)&Vl[r][cc] = t;
        }
        __syncthreads();
#pragma unroll
        for (int k = 0; k < 2; ++k) {
            int c    = tid + k * 256;     // Tl(2) x t(2) x vh(2) x lane(64)
            int Tl   = c >> 8;
            int t    = (c >> 7) & 1;
            int vh   = (c >> 6) & 1;
            int lane = c & 63;
            int ln = lane & 31, half = lane >> 5;
            union { short8 v; unsigned short u[8]; } o;
#pragma unroll
            for (int jj = 0; jj < 8; ++jj) {
                int r2 = t * 8 + jj;
                int m  = (r2 & 3) + 8 * (r2 >> 2) + 4 * half;
                o.u[jj] = f2bf(Vl[Tl * 32 + m][vh * 32 + ln]);
            }
            *(short8*)(vswz +
                ((((size_t)bh * 64 + (mt * 2 + Tl)) * 4 + t * 2 + vh) * 512)
                + lane * 8) = o.v;
        }
    } else {
        const float LOG2E = 1.4426950408889634f;
        int pb    = bid - 512;            // [0,128)
        int chunk = pb * 4 + (tid >> 6);  // [0,512): ((b*64+T)*4+ks)
        int lane  = tid & 63;
        int b = chunk >> 8, T = (chunk >> 2) & 63, ks = chunk & 3;
        int ln = lane & 31, hf = lane >> 5;
        const float* base = key + (((size_t)(b * LL + T * 32 + ln)) * HH) * DD
                                + ks * 16 + hf * 8;
        float s[8];
#pragma unroll
        for (int j = 0; j < 8; ++j) s[j] = 0.f;
#pragma unroll
        for (int v = 0; v < HH; ++v) {
            float4 f0 = *(const float4*)(base + v * DD);
            float4 f1 = *(const float4*)(base + v * DD + 4);
            s[0] += f0.x; s[1] += f0.y; s[2] += f0.z; s[3] += f0.w;
            s[4] += f1.x; s[5] += f1.y; s[6] += f1.z; s[7] += f1.w;
        }
        union { short8 v; unsigned u[4]; } o;
#pragma unroll
        for (int i = 0; i < 4; ++i)
            o.u[i] = pk_bf2(s[2 * i] * LOG2E, s[2 * i + 1] * LOG2E);
        *(short8*)(kswz + (size_t)chunk * 512 + lane * 8) = o.v;
    }
}

// ------------------------------- main kernel --------------------------------
// 512 blocks (16 bh x 32 tiles of 64 q-rows), 4 waves; wave wv owns keys
// [wv*512, wv*512+512) = swizzle tiles wv*16 .. wv*16+15.
__global__ __launch_bounds__(256, 3)
void attn_kernel(const float* __restrict__ query,
                 const unsigned short* __restrict__ kswz,
                 const unsigned short* __restrict__ vswz,
                 float* __restrict__ out) {
    int bid = blockIdx.x;
    int bh  = bid & 15;                // XCD swizzle: same-bh blocks share XCD L2
    int qt  = bid >> 4;                // [0,32), 64 q-rows each
    int h = bh & 7, b = bh >> 3;

    int tid  = threadIdx.x;
    int lane = tid & 63;
    int wv   = tid >> 6;
    int ln   = lane & 31;
    int half = lane >> 5;

    __shared__ float O2[2][64][68];    // pitch 68: breaks epilogue-read conflicts
    __shared__ float lsumL[4][128];
    __shared__ float invL[64];

    // Q B-frags for 2 q-groups, pre-scaled by 1/8 (exact in bf16)
    short8 qf[2][4];
#pragma unroll
    for (int g = 0; g < 2; ++g) {
        const float* qbase = query +
            (((size_t)(b * LL + qt * 64 + g * 32 + ln)) * HH + h) * DD;
#pragma unroll
        for (int ks = 0; ks < 4; ++ks) {
            const float4* qp = (const float4*)(qbase + ks * 16 + half * 8);
            float4 t0 = qp[0], t1 = qp[1];
            union { short8 v; unsigned u[4]; } uq;
            uq.u[0] = pk_bf2(t0.x * 0.125f, t0.y * 0.125f);
            uq.u[1] = pk_bf2(t0.z * 0.125f, t0.w * 0.125f);
            uq.u[2] = pk_bf2(t1.x * 0.125f, t1.y * 0.125f);
            uq.u[3] = pk_bf2(t1.z * 0.125f, t1.w * 0.125f);
            qf[g][ks] = uq.v;
        }
    }

    const unsigned short* kp0 = kswz + (((size_t)b * 64 + wv * 16) * 4) * 512
                                     + (size_t)lane * 8;
    const unsigned short* vp0 = vswz + (((size_t)bh * 64 + wv * 16) * 4) * 512
                                     + (size_t)lane * 8;

    float16v o00, o01, o10, o11;
#pragma unroll
    for (int i = 0; i < 16; ++i) { o00[i] = 0.f; o01[i] = 0.f; o10[i] = 0.f; o11[i] = 0.f; }
    float ls0a = 0.f, ls0b = 0.f, ls1a = 0.f, ls1b = 0.f;

#pragma unroll
    for (int it = 0; it < 16; ++it) {
        short8 kf[4], vf[4];
#pragma unroll
        for (int ks = 0; ks < 4; ++ks)
            kf[ks] = *(const short8*)(kp0 + it * 2048 + ks * 512);
#pragma unroll
        for (int u = 0; u < 4; ++u)
            vf[u] = *(const short8*)(vp0 + it * 2048 + u * 512);

#pragma unroll
        for (int g = 0; g < 2; ++g) {
            float16v sacc;
#pragma unroll
            for (int i = 0; i < 16; ++i) sacc[i] = 0.f;
#pragma unroll
            for (int ks = 0; ks < 4; ++ks)
                sacc = __builtin_amdgcn_mfma_f32_32x32x16_bf16(kf[ks], qf[g][ks], sacc, 0, 0, 0);

            union { short8 v[2]; unsigned u[8]; } pu;
#pragma unroll
            for (int i = 0; i < 8; ++i) {
                union { float f; unsigned u; } e0, e1;
                e0.f = exp2f(sacc[2 * i]);        // single v_exp_f32: log2e folded
                e1.f = exp2f(sacc[2 * i + 1]);    //   into kswz, 1/8 into Q
                if (g == 0) { ls0a += e0.f; ls0b += e1.f; }
                else        { ls1a += e0.f; ls1b += e1.f; }
                pu.u[i] = __builtin_amdgcn_perm(e1.u + 0x8000u, e0.u + 0x8000u, 0x07060302u);
            }

            if (g == 0) {
                o00 = __builtin_amdgcn_mfma_f32_32x32x16_bf16(pu.v[0], vf[0], o00, 0, 0, 0);
                o01 = __builtin_amdgcn_mfma_f32_32x32x16_bf16(pu.v[0], vf[1], o01, 0, 0, 0);
                o00 = __builtin_amdgcn_mfma_f32_32x32x16_bf16(pu.v[1], vf[2], o00, 0, 0, 0);
                o01 = __builtin_amdgcn_mfma_f32_32x32x16_bf16(pu.v[1], vf[3], o01, 0, 0, 0);
            } else {
                o10 = __builtin_amdgcn_mfma_f32_32x32x16_bf16(pu.v[0], vf[0], o10, 0, 0, 0);
                o11 = __builtin_amdgcn_mfma_f32_32x32x16_bf16(pu.v[0], vf[1], o11, 0, 0, 0);
                o10 = __builtin_amdgcn_mfma_f32_32x32x16_bf16(pu.v[1], vf[2], o10, 0, 0, 0);
                o11 = __builtin_amdgcn_mfma_f32_32x32x16_bf16(pu.v[1], vf[3], o11, 0, 0, 0);
            }
        }
    }

    // ---- epilogue: two-stage combine of 4 key-slice waves ----
    lsumL[wv][lane]      = ls0a + ls0b;
    lsumL[wv][64 + lane] = ls1a + ls1b;
    if (wv < 2) {
#pragma unroll
        for (int r = 0; r < 16; ++r) {
            int row = (r & 3) + 8 * (r >> 2) + 4 * half;
            O2[wv][row][ln]           = o00[r];
            O2[wv][row][32 + ln]      = o01[r];
            O2[wv][32 + row][ln]      = o10[r];
            O2[wv][32 + row][32 + ln] = o11[r];
        }
    }
    __syncthreads();
    if (wv >= 2) {
#pragma unroll
        for (int r = 0; r < 16; ++r) {
            int row = (r & 3) + 8 * (r >> 2) + 4 * half;
            O2[wv - 2][row][ln]           += o00[r];
            O2[wv - 2][row][32 + ln]      += o01[r];
            O2[wv - 2][32 + row][ln]      += o10[r];
            O2[wv - 2][32 + row][32 + ln] += o11[r];
        }
    }
    __syncthreads();

    if (tid < 64) {
        int g = tid >> 5, c = tid & 31;
        float s = 0.f;
#pragma unroll
        for (int w = 0; w < 4; ++w)
            s += lsumL[w][g * 64 + c] + lsumL[w][g * 64 + 32 + c];
        invL[tid] = 1.0f / s;
    }
    __syncthreads();

    int qrow = tid >> 2;               // [0,64)
    int c16  = (tid & 3) * 16;
    float inv = invL[qrow];
    float buf[16];
#pragma unroll
    for (int j = 0; j < 16; ++j)
        buf[j] = (O2[0][qrow][c16 + j] + O2[1][qrow][c16 + j]) * inv;
    float* ob = out + (((size_t)(b * LL + qt * 64 + qrow)) * HH + h) * DD + c16;
#pragma unroll
    for (int j = 0; j < 4; ++j)
        *(float4*)(ob + 4 * j) = make_float4(buf[4 * j], buf[4 * j + 1],
                                             buf[4 * j + 2], buf[4 * j + 3]);
}

extern "C" void kernel_launch(void* const* d_in, const int* in_sizes, int n_in,
                              void* d_out, int out_size, void* d_ws, size_t ws_size,
                              hipStream_t stream) {
    const float* query = (const float*)d_in[0];
    const float* key   = (const float*)d_in[1];
    const float* value = (const float*)d_in[2];
    float* out = (float*)d_out;

    unsigned short* kswz = (unsigned short*)d_ws;                       // 512 KiB
    unsigned short* vswz = (unsigned short*)((char*)d_ws + 512 * 1024); // 4 MiB
    // ws_size measured at 256 MiB (harness poison fill); 4.5 MiB used, flat.

    prep_kernel<<<640, 256, 0, stream>>>(key, value, kswz, vswz);
    attn_kernel<<<512, 256, 0, stream>>>(query, kswz, vswz, out);
}